// Round 1
// 707.215 us; speedup vs baseline: 1.0796x; 1.0796x over previous
//
#include <hip/hip_runtime.h>

// ChunkedCrossAttention on MI355X (gfx950) — round 4.
// Changes vs round 3:
//  - K/V projection rewritten as 256x256-tile 8-phase kernel (gemm_kv):
//    8 waves, 128 KiB LDS double-buffer, counted vmcnt(4) gates (never 0 in
//    the main loop), setprio(1) around each 16-MFMA cluster. A stays fp32
//    with fused cast: loads issued at ph1, packed+ds_written at ph4 (T14
//    split); B staged via global_load_lds 2 tiles ahead. End-of-K staging
//    kept UNCONDITIONAL via k0&1023 wrap so compiler waitcnt counting stays
//    static (a guard would force conservative vmcnt(0) and kill the pipe).
//  - prep_k weight transpose now goes through a 64x64 LDS tile (old version
//    read W at stride 2KB per lane -> ~16x fetch amplification).
//  - RoPE-K / V-transpose epilogues, attn, gemm_out, Q-projection unchanged.

#define DEV __device__ __forceinline__

typedef __bf16 bf16x8 __attribute__((ext_vector_type(8)));
typedef float f32x4 __attribute__((ext_vector_type(4)));

DEV unsigned short f2bf(float f) {
  union { float f; unsigned int u; } v; v.f = f;
  unsigned int u = v.u;
  unsigned int r = (u + 0x7FFFu + ((u >> 16) & 1u)) >> 16;  // RNE
  return (unsigned short)r;
}
DEV float bf2f(unsigned short h) {
  union { unsigned int u; float f; } v; v.u = ((unsigned int)h) << 16;
  return v.f;
}
// pack two fp32 -> two bf16 (RTZ): result = [bf16(lo), bf16(hi)]
DEV unsigned int pkbf(unsigned int hi, unsigned int lo) {
  return __builtin_amdgcn_perm(hi, lo, 0x07060302u);
}

// async global->LDS, 16B per lane; LDS dest = wave-uniform base + lane*16
DEV void ldst16(const void* g, void* l) {
  __builtin_amdgcn_global_load_lds(
      (const __attribute__((address_space(1))) void*)g,
      (__attribute__((address_space(3))) void*)l, 16, 0, 0);
}

DEV void bar() { __builtin_amdgcn_s_barrier(); }
#define LGKM0 asm volatile("s_waitcnt lgkmcnt(0)" ::: "memory")
#define VMCNT4 asm volatile("s_waitcnt vmcnt(4)" ::: "memory")
#define VMCNT0 asm volatile("s_waitcnt vmcnt(0)" ::: "memory")

// ---------------------------------------------------------------------------
// prep: weight transpose+cast (+SCALE fold) via LDS tiles, zero rows 0..62
// per batch of out, rope cos/sin tables. One launch, grid 796.
//   blk [0,512):   transpose tiles (128 per matrix: Wq, Wk, Wv, Wo)
//   blk [512,764): zero rows
//   blk [764,796): rope tables
// ---------------------------------------------------------------------------
__global__ __launch_bounds__(256) void prep_k(const float* __restrict__ Wq,
                                              const float* __restrict__ Wk,
                                              const float* __restrict__ Wv,
                                              const float* __restrict__ Wo,
                                              const float* __restrict__ qpe,
                                              const float* __restrict__ kpe,
                                              unsigned short* __restrict__ Wqt,
                                              unsigned short* __restrict__ Wkt,
                                              unsigned short* __restrict__ Wvt,
                                              unsigned short* __restrict__ Wot,
                                              float* __restrict__ ck, float* __restrict__ sk,
                                              float* __restrict__ cq, float* __restrict__ sq,
                                              float* __restrict__ out) {
  __shared__ float tl[64][65];
  int blk = blockIdx.x;
  int tid = threadIdx.x;
  if (blk < 512) {
    int mat = blk >> 7, loc = blk & 127;
    const float* W;
    unsigned short* Wt;
    int R, C;
    float scale = 1.0f;
    if (mat == 0)      { W = Wq; Wt = Wqt; R = 1024; C = 512; scale = 0.125f; }
    else if (mat == 1) { W = Wk; Wt = Wkt; R = 1024; C = 512; }
    else if (mat == 2) { W = Wv; Wt = Wvt; R = 1024; C = 512; }
    else               { W = Wo; Wt = Wot; R = 512;  C = 1024; }
    int nct = C >> 6;
    int rt = loc / nct, ct = loc % nct;
    int r0 = rt << 6, c0 = ct << 6;
    #pragma unroll
    for (int i = 0; i < 16; ++i) {
      int flat = i * 256 + tid;
      int rr = flat >> 6, cc = flat & 63;
      tl[rr][cc] = W[(size_t)(r0 + rr) * C + c0 + cc] * scale;
    }
    __syncthreads();
    #pragma unroll
    for (int i = 0; i < 16; ++i) {
      int flat = i * 256 + tid;
      int cc = flat >> 6, rr = flat & 63;
      Wt[(size_t)(c0 + cc) * R + r0 + rr] = f2bf(tl[rr][cc]);
    }
  } else if (blk < 764) {                  // zero rows 0..62 of each batch
    int r = blk - 512;
    int b = r / 63, rr = r % 63;
    float4 z = {0.f, 0.f, 0.f, 0.f};
    *(float4*)(out + (((size_t)(b * 4096 + rr)) << 10) + tid * 4) = z;
  } else {                                 // rope tables
    int t = (blk - 764) * 256 + tid;       // 0..8191
    float f = kpe[t];
    ck[t] = cosf(f);
    sk[t] = sinf(f);
    if (t < 64) {
      float g = qpe[63 * 64 + t];
      cq[t] = cosf(g);
      sq[t] = sinf(g);
    }
  }
}

// ---------------------------------------------------------------------------
// Q projection (unchanged, round-3 kernel, MODE 0 only launched):
// C(Mx512) = cast(Af)(MxK) * B^T(512xK); A reg-staged fp32->bf16 pack,
// B via global_load_lds; RoPE-Q fused on rows m%64==0.
// ---------------------------------------------------------------------------
template <int MODE>
__global__ __launch_bounds__(256) void gemm_proj(const float* __restrict__ Af,
                                                 const unsigned short* __restrict__ B0,
                                                 const unsigned short* __restrict__ B1,
                                                 unsigned short* __restrict__ out0,
                                                 unsigned short* __restrict__ out1,
                                                 const float* __restrict__ ck,
                                                 const float* __restrict__ sk,
                                                 const float* __restrict__ cq,
                                                 const float* __restrict__ sq) {
  __shared__ unsigned short sh[16384];  // As = sh[0:8192], Bs = sh[8192:16384]
  unsigned short* As = sh;
  unsigned short* Bs = sh + 8192;
  const int K = 1024;

  int id = blockIdx.x;
  int x, y, z;
  if (MODE == 0) { x = (id & 7) + 8 * (id >> 5); y = (id >> 3) & 3; z = 0; }
  else           { x = (id & 7) + 8 * (id >> 6); int j = (id >> 3) & 7; y = j & 3; z = j >> 2; }
  const unsigned short* B = z ? B1 : B0;
  int m0 = x * 128, n0 = y * 128;
  int tid = threadIdx.x, w = tid >> 6, lane = tid & 63;
  int wm = (w & 1) * 64, wn = (w >> 1) * 64;
  int Lrow = lane >> 3, Lc = lane & 7;
  int srcC = Lc ^ (Lrow & 7);

  const float* asrc[4];
  bool avalid[4];
  #pragma unroll
  for (int q = 0; q < 4; ++q) {
    int t = w * 4 + q;
    int gm = m0 + t * 8 + Lrow;
    if (MODE == 0) {
      int b = gm >> 12, p = gm & 4095;
      avalid[q] = (p <= 4032);
      asrc[q] = Af + (((size_t)(b << 12) + p + 63) << 10) + srcC * 8;
    } else {
      avalid[q] = true;
      asrc[q] = Af + (size_t)gm * 1024 + srcC * 8;
    }
  }

  f32x4 acc[4][4] = {};

  for (int k0 = 0; k0 < K; k0 += 64) {
    #pragma unroll
    for (int q = 0; q < 4; ++q) {
      int t = w * 4 + q;
      uint4 lo = {0, 0, 0, 0}, hi = {0, 0, 0, 0};
      if (avalid[q]) {
        lo = *(const uint4*)(asrc[q] + k0);
        hi = *(const uint4*)(asrc[q] + k0 + 4);
      }
      uint4 pk;
      pk.x = pkbf(lo.y, lo.x);
      pk.y = pkbf(lo.w, lo.z);
      pk.z = pkbf(hi.y, hi.x);
      pk.w = pkbf(hi.w, hi.z);
      *(uint4*)((char*)As + t * 1024 + lane * 16) = pk;
      ldst16(B + (size_t)(n0 + t * 8 + Lrow) * K + (k0 + srcC * 8), (char*)Bs + t * 1024);
    }
    __syncthreads();
    #pragma unroll
    for (int k32 = 0; k32 < 2; ++k32) {
      int c = k32 * 4 + (lane >> 4);
      bf16x8 af[4], bfr[4];
      #pragma unroll
      for (int mt = 0; mt < 4; ++mt) {
        int m = wm + mt * 16 + (lane & 15);
        af[mt] = *(const bf16x8*)((const char*)As + m * 128 + (c ^ (m & 7)) * 16);
      }
      #pragma unroll
      for (int nt = 0; nt < 4; ++nt) {
        int n = wn + nt * 16 + (lane & 15);
        bfr[nt] = *(const bf16x8*)((const char*)Bs + n * 128 + (c ^ (n & 7)) * 16);
      }
      #pragma unroll
      for (int mt = 0; mt < 4; ++mt)
        #pragma unroll
        for (int nt = 0; nt < 4; ++nt)
          acc[mt][nt] = __builtin_amdgcn_mfma_f32_16x16x32_bf16(af[mt], bfr[nt], acc[mt][nt], 0, 0, 0);
    }
    __syncthreads();
  }

  // C/D layout: col = lane&15, row = (lane>>4)*4 + reg.
  if (MODE == 0) {
    #pragma unroll
    for (int mt = 0; mt < 4; ++mt)
      #pragma unroll
      for (int nt = 0; nt < 4; ++nt)
        #pragma unroll
        for (int r = 0; r < 4; ++r) {
          int m = m0 + wm + mt * 16 + (lane >> 4) * 4 + r;
          int n = n0 + wn + nt * 16 + (lane & 15);
          float val = acc[mt][nt][r];
          if ((m & 63) == 0) {  // only chunk-row 0 gets Q-RoPE
            int d = nt * 16 + (lane & 15);
            float partner = acc[mt][nt ^ 2][r];
            val = val * cq[d] + (nt < 2 ? -partner : partner) * sq[d];
          }
          out0[(size_t)m * 512 + n] = f2bf(val);
        }
  } else if (z == 0) {
    #pragma unroll
    for (int mt = 0; mt < 4; ++mt)
      #pragma unroll
      for (int r = 0; r < 4; ++r) {
        int m = m0 + wm + mt * 16 + (lane >> 4) * 4 + r;
        int fib = (m & 127) * 64;
        #pragma unroll
        for (int nt = 0; nt < 4; ++nt) {
          int n = n0 + wn + nt * 16 + (lane & 15);
          int d = nt * 16 + (lane & 15);
          float partner = acc[mt][nt ^ 2][r];
          float val = acc[mt][nt][r] * ck[fib + d] + (nt < 2 ? -partner : partner) * sk[fib + d];
          out0[(size_t)m * 512 + n] = f2bf(val);
        }
      }
  } else {
    #pragma unroll
    for (int mt = 0; mt < 4; ++mt)
      #pragma unroll
      for (int nt = 0; nt < 4; ++nt)
        #pragma unroll
        for (int r = 0; r < 4; ++r) {
          int ml = wm + mt * 16 + (lane >> 4) * 4 + r;
          int nl = wn + nt * 16 + (lane & 15);
          int mc = ml >> 3, me = ml & 7;
          *(unsigned short*)((char*)sh + nl * 256 + ((mc ^ (nl & 15)) * 16) + me * 2) =
              f2bf(acc[mt][nt][r]);
        }
    __syncthreads();
    #pragma unroll
    for (int i = 0; i < 8; ++i) {
      int flat = i * 256 + tid;
      int nl = flat >> 4, mc = flat & 15;
      uint4 v = *(const uint4*)((const char*)sh + nl * 256 + ((mc ^ (nl & 15)) * 16));
      *(uint4*)(out1 + (size_t)(n0 + nl) * 65536 + m0 + mc * 8) = v;
    }
  }
}

// ---------------------------------------------------------------------------
// gemm_kv: K/V projection, 256x256 tile, BK=64, 8 waves, 8-phase schedule.
//   C(65536x512) = cast(ctx fp32)(65536x1024) @ Wt^T(512x1024), z=0 -> K
//   (+RoPE) to kb, z=1 -> V transposed to vtg.
// LDS: A0|A1|B0|B1, each 256x64 bf16 = 32 KB, swizzled chunk layout
//   phys_chunk(row,c) = row*8 + (c ^ (row&7)), chunk = 16B.
// Schedule per iteration (2 K-tiles), per phase:
//   {ds_read frags | stage} -> barrier -> setprio(1) 16xMFMA setprio(0) -> barrier
//   ph1: read B-frags(8)+A-frags mt01; issue 8 fp32 A-loads (tile t0+1)
//   ph2: A mt23
//   ph3: A mt45; gload_lds B(t0+2) half0  [lands in B0, whose reads ended ph1]
//   ph4: A mt67; gload_lds B(t0+2) half1; pack+ds_write A(t0+1)->A1
//        (compiler auto-wait = counted vmcnt(4)); lgkmcnt(0); vmcnt(4) gate
//   ph5-8: mirror on A1/B1, staging A(t0+2)->A0 and B(t1+2)->B1.
// k-offsets wrapped &1023 at the tail: stages stay unconditional (static
// waitcnt counting) and the junk tiles are never consumed.
// ---------------------------------------------------------------------------
DEV bf16x8 rdfrag(const unsigned short* b, int row, int c) {
  return *(const bf16x8*)((const char*)b + row * 128 + ((c ^ (row & 7)) << 4));
}

DEV void rdA(const unsigned short* bufA, int wm, int ln15, int l4, int mtb,
             bf16x8 (&af)[2][2]) {
  #pragma unroll
  for (int mq = 0; mq < 2; ++mq)
    #pragma unroll
    for (int kk = 0; kk < 2; ++kk)
      af[mq][kk] = rdfrag(bufA, wm + (mtb + mq) * 16 + ln15, kk * 4 + l4);
}

DEV void rdB(const unsigned short* bufB, int wn, int ln15, int l4, bf16x8 (&bf)[4][2]) {
  #pragma unroll
  for (int nt = 0; nt < 4; ++nt)
    #pragma unroll
    for (int kk = 0; kk < 2; ++kk)
      bf[nt][kk] = rdfrag(bufB, wn + nt * 16 + ln15, kk * 4 + l4);
}

template <int MTB>
DEV void mfma16(const bf16x8 (&af)[2][2], const bf16x8 (&bf)[4][2], f32x4 (&acc)[8][4]) {
  __builtin_amdgcn_s_setprio(1);
  #pragma unroll
  for (int mq = 0; mq < 2; ++mq)
    #pragma unroll
    for (int nt = 0; nt < 4; ++nt)
      #pragma unroll
      for (int kk = 0; kk < 2; ++kk)
        acc[MTB + mq][nt] = __builtin_amdgcn_mfma_f32_16x16x32_bf16(
            af[mq][kk], bf[nt][kk], acc[MTB + mq][nt], 0, 0, 0);
  __builtin_amdgcn_s_setprio(0);
}

DEV void aload(const float* Af, int m0, int rowt, int csrc, int k0, uint4 (&al)[8]) {
  #pragma unroll
  for (int q = 0; q < 4; ++q) {
    const float* s = Af + (size_t)(m0 + q * 64 + rowt) * 1024 + k0 + csrc * 8;
    al[2 * q] = *(const uint4*)s;
    al[2 * q + 1] = *(const uint4*)(s + 4);
  }
}

DEV void apack(unsigned short* bufA, int tid, const uint4 (&al)[8]) {
  #pragma unroll
  for (int q = 0; q < 4; ++q) {
    uint4 pk;
    pk.x = pkbf(al[2 * q].y, al[2 * q].x);
    pk.y = pkbf(al[2 * q].w, al[2 * q].z);
    pk.z = pkbf(al[2 * q + 1].y, al[2 * q + 1].x);
    pk.w = pkbf(al[2 * q + 1].w, al[2 * q + 1].z);
    *(uint4*)((char*)bufA + ((q * 512 + tid) << 4)) = pk;
  }
}

DEV void bstage(unsigned short* bufB, const unsigned short* Bsrc, int n0, int w,
                int Lrow, int srcC, int k0, int h) {
  #pragma unroll
  for (int qq = 0; qq < 2; ++qq) {
    int q = 2 * h + qq;
    ldst16(Bsrc + (size_t)(n0 + q * 64 + w * 8 + Lrow) * 1024 + k0 + srcC * 8,
           (char*)bufB + ((q * 512 + w * 64) << 4));
  }
}

__global__ __launch_bounds__(512, 2) void gemm_kv(const float* __restrict__ Af,
                                                  const unsigned short* __restrict__ Bk,
                                                  const unsigned short* __restrict__ Bv,
                                                  unsigned short* __restrict__ kb,
                                                  unsigned short* __restrict__ vtg,
                                                  const float* __restrict__ ck,
                                                  const float* __restrict__ sk) {
  __shared__ unsigned short sh[65536];  // 128 KiB
  unsigned short* A0b = sh;
  unsigned short* A1b = sh + 16384;
  unsigned short* B0b = sh + 32768;
  unsigned short* B1b = sh + 49152;

  int id = blockIdx.x;                      // 1024 blocks
  int x = (id & 7) + 8 * (id >> 5);         // 4 yz-siblings of an A panel share
  int j = (id >> 3) & 3;                    // an XCD (ids equal mod 8)
  int y = j & 1, z = j >> 1;
  const unsigned short* Bz = z ? Bv : Bk;
  int m0 = x << 8, n0 = y << 8;

  int tid = threadIdx.x, w = tid >> 6, lane = tid & 63;
  int wm = (w & 1) * 128, wn = (w >> 1) * 64;
  int ln15 = lane & 15, l4 = lane >> 4;
  int Lrow = lane >> 3;
  int srcC = (lane & 7) ^ (Lrow & 7);
  int rowt = tid >> 3;
  int csrc = (tid & 7) ^ (rowt & 7);

  f32x4 acc[8][4] = {};
  uint4 al[8];

  // prologue: A(0) via regs, B(0) and B(1) via gload_lds; keep B(1) in flight
  aload(Af, m0, rowt, csrc, 0, al);
  bstage(B0b, Bz, n0, w, Lrow, srcC, 0, 0);
  bstage(B0b, Bz, n0, w, Lrow, srcC, 0, 1);
  bstage(B1b, Bz, n0, w, Lrow, srcC, 64, 0);
  bstage(B1b, Bz, n0, w, Lrow, srcC, 64, 1);
  apack(A0b, tid, al);                      // auto-wait: counted vmcnt(8)
  LGKM0;
  VMCNT4;                                   // B(0) done, B(1) stays in flight
  bar();

  for (int it = 0; it < 8; ++it) {
    const int k0a = it * 128;
    bf16x8 af[2][2], bf[4][2];

    // ---- tile t0 = 2it (A0b/B0b) ----
    rdB(B0b, wn, ln15, l4, bf);
    rdA(A0b, wm, ln15, l4, 0, af);
    aload(Af, m0, rowt, csrc, k0a + 64, al);           // A(t0+1)
    bar();
    mfma16<0>(af, bf, acc);
    bar();

    rdA(A0b, wm, ln15, l4, 2, af);
    bar();
    mfma16<2>(af, bf, acc);
    bar();

    rdA(A0b, wm, ln15, l4, 4, af);
    bstage(B0b, Bz, n0, w, Lrow, srcC, (k0a + 128) & 1023, 0);  // B(t0+2)
    bar();
    mfma16<4>(af, bf, acc);
    bar();

    rdA(A0b, wm, ln15, l4, 6, af);
    bstage(B0b, Bz, n0, w, Lrow, srcC, (k0a + 128) & 1023, 1);
    apack(A1b, tid, al);                    // auto-wait: counted vmcnt(4)
    LGKM0;
    VMCNT4;                                 // gate: B(t1) drained, B(t0+2) flies
    bar();
    mfma16<6>(af, bf, acc);
    bar();

    // ---- tile t1 = 2it+1 (A1b/B1b) ----
    rdB(B1b, wn, ln15, l4, bf);
    rdA(A1b, wm, ln15, l4, 0, af);
    aload(Af, m0, rowt, csrc, (k0a + 128) & 1023, al); // A(t0+2)
    bar();
    mfma16<0>(af, bf, acc);
    bar();

    rdA(A1b, wm, ln15, l4, 2, af);
    bar();
    mfma16<2>(af, bf, acc);
    bar();

    rdA(A1b, wm, ln15, l4, 4, af);
    bstage(B1b, Bz, n0, w, Lrow, srcC, (k0a + 192) & 1023, 0);  // B(t1+2)
    bar();
    mfma16<4>(af, bf, acc);
    bar();

    rdA(A1b, wm, ln15, l4, 6, af);
    bstage(B1b, Bz, n0, w, Lrow, srcC, (k0a + 192) & 1023, 1);
    apack(A0b, tid, al);
    LGKM0;
    VMCNT4;
    bar();
    mfma16<6>(af, bf, acc);
    bar();
  }

  // drain wrapped tail stages before LDS reuse / exit
  VMCNT0;
  bar();

  if (z == 0) {  // K with RoPE: fi = (m&127)*64 + d
    #pragma unroll
    for (int mt = 0; mt < 8; ++mt)
      #pragma unroll
      for (int r = 0; r < 4; ++r) {
        int m = m0 + wm + mt * 16 + l4 * 4 + r;
        int fib = (m & 127) << 6;
        #pragma unroll
        for (int nt = 0; nt < 4; ++nt) {
          int d = nt * 16 + ln15;
          float partner = acc[mt][nt ^ 2][r];
          float val = acc[mt][nt][r] * ck[fib + d] + (nt < 2 ? -partner : partner) * sk[fib + d];
          kb[(size_t)m * 512 + n0 + wn + d] = f2bf(val);
        }
      }
  } else {  // V: transpose through LDS (256 rows x 512B), store vtg[n][m]
    #pragma unroll
    for (int mt = 0; mt < 8; ++mt)
      #pragma unroll
      for (int nt = 0; nt < 4; ++nt)
        #pragma unroll
        for (int r = 0; r < 4; ++r) {
          int ml = wm + mt * 16 + l4 * 4 + r;
          int nl = wn + nt * 16 + ln15;
          int mc = ml >> 3, me = ml & 7;
          *(unsigned short*)((char*)sh + nl * 512 + ((mc ^ (nl & 31)) << 4) + me * 2) =
              f2bf(acc[mt][nt][r]);
        }
    __syncthreads();
    #pragma unroll
    for (int i = 0; i < 16; ++i) {
      int flat = i * 512 + tid;
      int nl = flat >> 5, mc = flat & 31;
      uint4 v = *(const uint4*)((const char*)sh + nl * 512 + ((mc ^ (nl & 31)) << 4));
      *(uint4*)(vtg + (size_t)(n0 + nl) * 65536 + m0 + mc * 8) = v;
    }
  }
}

// ---------------------------------------------------------------------------
// Output GEMM (unchanged): out fp32 = A(16384x512) * Wo^T(1024x512) + bias,
// row-shifted: out[b, t+63] = row(b*4096+t) for t<=4032.
// ---------------------------------------------------------------------------
__global__ __launch_bounds__(256) void gemm_out(const unsigned short* __restrict__ A,
                                                const unsigned short* __restrict__ B,
                                                const float* __restrict__ bias,
                                                float* __restrict__ out) {
  __shared__ unsigned short sh[16384];
  unsigned short* As = sh;
  unsigned short* Bs = sh + 8192;
  const int K = 512, N = 1024;
  int id = blockIdx.x;
  int x = (id & 7) + 8 * (id >> 6), y = (id >> 3) & 7;
  int m0 = x * 128, n0 = y * 128;
  int tid = threadIdx.x, w = tid >> 6, lane = tid & 63;
  int wm = (w & 1) * 64, wn = (w >> 1) * 64;
  int Lrow = lane >> 3, Lc = lane & 7;
  int srcC = Lc ^ (Lrow & 7);

  f32x4 acc[4][4] = {};

  for (int k0 = 0; k0 < K; k0 += 64) {
    #pragma unroll
    for (int q = 0; q < 4; ++q) {
      int t = w * 4 + q;
      ldst16(A + (size_t)(m0 + t * 8 + Lrow) * K + (k0 + srcC * 8), (char*)As + t * 1024);
      ldst16(B + (size_t)(n0 + t * 8 + Lrow) * K + (k0 + srcC * 8), (char*)Bs + t * 1024);
    }
    __syncthreads();
    #pragma unroll
    for (int k32 = 0; k32 < 2; ++k32) {
      int c = k32 * 4 + (lane >> 4);
      bf16x8 af[4], bfr[4];
      #pragma unroll
      for (int mt = 0; mt < 4; ++mt) {
        int m = wm + mt * 16 + (lane & 15);
        af[mt] = *(const bf16x8*)((const char*)As + m * 128 + (c ^ (m & 7)) * 16);
      }
      #pragma unroll
      for (int nt = 0; nt < 4; ++nt) {
        int n = wn + nt * 16 + (lane & 15);
        bfr[nt] = *(const bf16x8*)((const char*)Bs + n * 128 + (c ^ (n & 7)) * 16);
      }
      #pragma unroll
      for (int mt = 0; mt < 4; ++mt)
        #pragma unroll
        for (int nt = 0; nt < 4; ++nt)
          acc[mt][nt] = __builtin_amdgcn_mfma_f32_16x16x32_bf16(af[mt], bfr[nt], acc[mt][nt], 0, 0, 0);
    }
    __syncthreads();
  }
  #pragma unroll
  for (int mt = 0; mt < 4; ++mt)
    #pragma unroll
    for (int nt = 0; nt < 4; ++nt)
      #pragma unroll
      for (int r = 0; r < 4; ++r) {
        int m = m0 + wm + mt * 16 + (lane >> 4) * 4 + r;
        int n = n0 + wn + nt * 16 + (lane & 15);
        int b = m >> 12, t = m & 4095;
        if (t <= 4032)
          out[((size_t)((b << 12) + t + 63)) * N + n] = acc[mt][nt][r] + bias[n];
      }
}

// ---------------------------------------------------------------------------
// Fused attention per (bc, h) (unchanged).
// ---------------------------------------------------------------------------
__global__ __launch_bounds__(256) void attn_kernel(const unsigned short* __restrict__ qb,
                                                   const unsigned short* __restrict__ kb,
                                                   const unsigned short* __restrict__ vtg,
                                                   const float* __restrict__ nullk,
                                                   const float* __restrict__ nullv,
                                                   unsigned short* __restrict__ ob) {
  __shared__ unsigned short qs[64 * 64];    // 8 KB  [i][d]
  __shared__ unsigned short ks[256 * 64];   // 32 KB [j][d]; reused as vt[d][j]
  __shared__ unsigned short ps[64 * 256];   // 32 KB [i][j]
  __shared__ float rnull[64];
  __shared__ float rsum[64];
  int id = blockIdx.x;
  int bc = (id & 7) + 8 * (id >> 6);
  int h = (id >> 3) & 7;
  int tid = threadIdx.x, w = tid >> 6, lane = tid & 63;
  int Lrow = lane >> 3, Lc = lane & 7, srcC = Lc ^ (Lrow & 7);

  #pragma unroll
  for (int q8 = 0; q8 < 2; ++q8) {
    int t = w * 2 + q8;
    ldst16(qb + (size_t)(bc * 64 + t * 8 + Lrow) * 512 + h * 64 + srcC * 8, (char*)qs + t * 1024);
  }
  #pragma unroll
  for (int q8 = 0; q8 < 8; ++q8) {
    int t = w * 8 + q8;
    ldst16(kb + (size_t)(bc * 256 + t * 8 + Lrow) * 512 + h * 64 + srcC * 8, (char*)ks + t * 1024);
  }
  __syncthreads();

  // null-key sims: 4 lanes per row, 16 d each, combine via shuffles.
  {
    int rl = lane >> 2, part = lane & 3;
    int row = w * 16 + rl;
    float s = 0.f;
    #pragma unroll
    for (int e = 0; e < 16; ++e) {
      int d = part * 16 + e;
      unsigned short qv = *(const unsigned short*)((const char*)qs + row * 128 +
                                                   (((d >> 3) ^ (row & 7)) * 16) + (d & 7) * 2);
      s += bf2f(qv) * nullk[h * 64 + d];
    }
    s += __shfl_xor(s, 1);
    s += __shfl_xor(s, 2);
    if (part == 0) rnull[row] = __expf(s);
  }

  // sim: wave w owns rows [16w,16w+16), 16 n-tiles of 16 keys.
  f32x4 acc[16] = {};
  #pragma unroll
  for (int k32 = 0; k32 < 2; ++k32) {
    int c = k32 * 4 + (lane >> 4);
    int m = w * 16 + (lane & 15);
    bf16x8 a = *(const bf16x8*)((const char*)qs + m * 128 + (c ^ (m & 7)) * 16);
    #pragma unroll
    for (int nt = 0; nt < 16; ++nt) {
      int n = nt * 16 + (lane & 15);
      bf16x8 b = *(const bf16x8*)((const char*)ks + n * 128 + (c ^ (n & 7)) * 16);
      acc[nt] = __builtin_amdgcn_mfma_f32_16x16x32_bf16(a, b, acc[nt], 0, 0, 0);
    }
  }

  // exp + row-sum (no max subtraction).
  int g = lane >> 4;
  #pragma unroll
  for (int r = 0; r < 4; ++r) {
    int row = w * 16 + g * 4 + r;
    float s = 0.f;
    #pragma unroll
    for (int nt = 0; nt < 16; ++nt) {
      float p = __expf(acc[nt][r]);
      acc[nt][r] = p;
      s += p;
    }
    s += __shfl_xor(s, 1);
    s += __shfl_xor(s, 2);
    s += __shfl_xor(s, 4);
    s += __shfl_xor(s, 8);
    if ((lane & 15) == 0) rsum[row] = s + rnull[row];
  }

  // P -> LDS bf16 (A-operand layout for PV).
  #pragma unroll
  for (int nt = 0; nt < 16; ++nt)
    #pragma unroll
    for (int r = 0; r < 4; ++r) {
      int row = w * 16 + g * 4 + r;
      int col = nt * 16 + (lane & 15);
      *(unsigned short*)((char*)ps + row * 512 + (((col >> 3) ^ (row & 7)) * 16) + (col & 7) * 2) =
          f2bf(acc[nt][r]);
    }
  __syncthreads();  // all waves done reading ks

  // stage V^T (pre-transposed in global) into ks via ldst16.
  #pragma unroll
  for (int q8 = 0; q8 < 8; ++q8) {
    int t = w * 8 + q8;                 // 1KB region = rows 2t, 2t+1
    int dd = t * 2 + (lane >> 5);
    int cl = (lane & 31) ^ (dd & 7);    // logical chunk for this phys slot
    ldst16(vtg + (size_t)(h * 64 + dd) * 65536 + bc * 256 + cl * 8, (char*)ks + t * 1024);
  }
  __syncthreads();

  // o = P v : k over 256 keys, 4 n-tiles of d.
  f32x4 oacc[4] = {};
  #pragma unroll
  for (int k32 = 0; k32 < 8; ++k32) {
    int c = k32 * 4 + (lane >> 4);
    int m = w * 16 + (lane & 15);
    bf16x8 a = *(const bf16x8*)((const char*)ps + m * 512 + (c ^ (m & 7)) * 16);
    #pragma unroll
    for (int nt = 0; nt < 4; ++nt) {
      int n = nt * 16 + (lane & 15);
      bf16x8 b = *(const bf16x8*)((const char*)ks + n * 512 + (c ^ (n & 7)) * 16);
      oacc[nt] = __builtin_amdgcn_mfma_f32_16x16x32_bf16(a, b, oacc[nt], 0, 0, 0);
    }
  }
  #pragma unroll
  for (int nt = 0; nt < 4; ++nt)
    #pragma unroll
    for (int r = 0; r < 4; ++r) {
      int row = w * 16 + g * 4 + r;
      int d = nt * 16 + (lane & 15);
      float o = oacc[nt][r] + rnull[row] * nullv[h * 64 + d];
      o /= rsum[row];
      ob[((size_t)(bc * 64 + row) * 8 + h) * 64 + d] = f2bf(o);
    }
}

// ---------------------------------------------------------------------------
extern "C" void kernel_launch(void* const* d_in, const int* in_sizes, int n_in,
                              void* d_out, int out_size, void* d_ws, size_t ws_size,
                              hipStream_t stream) {
  const float* x = (const float*)d_in[0];
  const float* ctx = (const float*)d_in[1];
  const float* qpe = (const float*)d_in[2];
  const float* kpe = (const float*)d_in[3];
  const float* Wq = (const float*)d_in[4];
  const float* Wk = (const float*)d_in[5];
  const float* Wv = (const float*)d_in[6];
  const float* Wo = (const float*)d_in[7];
  const float* bo = (const float*)d_in[8];
  const float* nk = (const float*)d_in[9];
  const float* nv = (const float*)d_in[10];
  float* out = (float*)d_out;
  char* ws = (char*)d_ws;

  unsigned short* Wqt  = (unsigned short*)(ws + 0);          // 1,048,576
  unsigned short* Wkt  = (unsigned short*)(ws + 1048576);    // 1,048,576
  unsigned short* Wvt  = (unsigned short*)(ws + 2097152);    // 1,048,576
  unsigned short* Wot  = (unsigned short*)(ws + 3145728);    // 1,048,576
  unsigned short* qb   = (unsigned short*)(ws + 4194304);    // 16,777,216
  unsigned short* kb   = (unsigned short*)(ws + 20971520);   // 67,108,864
  unsigned short* vtg  = (unsigned short*)(ws + 88080384);   // 67,108,864 (V^T: [512][65536])
  unsigned short* obuf = (unsigned short*)(ws + 155189248);  // 16,777,216
  float* cosk = (float*)(ws + 171966464);                    // 32,768
  float* sink = (float*)(ws + 171999232);                    // 32,768
  float* cosq = (float*)(ws + 172032000);                    // 256
  float* sinq = (float*)(ws + 172032256);                    // 256

  prep_k<<<796, 256, 0, stream>>>(Wq, Wk, Wv, Wo, qpe, kpe, Wqt, Wkt, Wvt, Wot,
                                  cosk, sink, cosq, sinq, out);

  // Q projection (16384x1024)@(1024x512), fp32-A fused cast + shift, RoPE fused
  gemm_proj<0><<<512, 256, 0, stream>>>(x, Wqt, Wqt, qb, nullptr,
                                        cosk, sink, cosq, sinq);
  // K+V projection (65536x1024)@(1024x512) x2: 256^2-tile 8-phase kernel;
  // K RoPE'd, V transposed
  gemm_kv<<<1024, 512, 0, stream>>>(ctx, Wkt, Wvt, kb, vtg, cosk, sink);

  attn_kernel<<<2048, 256, 0, stream>>>(qb, kb, vtg, nk, nv, obuf);

  // Output: (16384x512)@(512x1024) + bias, shifted rows
  gemm_out<<<1024, 256, 0, stream>>>(obuf, Wot, bo, out);
}